// Round 2
// baseline (755.829 us; speedup 1.0000x reference)
//
#include <hip/hip_runtime.h>

#define Bz 8
#define Nz 1024
#define Dz 1024
#define Hz 16
#define HDz 64
#define DFFz 4096

typedef __attribute__((ext_vector_type(8))) __bf16 bh8;
typedef __attribute__((ext_vector_type(4))) __bf16 bh4;
typedef __attribute__((ext_vector_type(4))) float f4;

#define GLOAD16(gp, lp) __builtin_amdgcn_global_load_lds( \
    (__attribute__((address_space(1))) void*)(gp), \
    (__attribute__((address_space(3))) void*)(lp), 16, 0, 0)

// ---------------- fp32 -> bf16 convert ----------------
__global__ __launch_bounds__(256) void cvt_k(const float* __restrict__ in,
                                             __bf16* __restrict__ out, int n4) {
    int i = blockIdx.x * 256 + threadIdx.x;
    if (i < n4) {
        float4 v = ((const float4*)in)[i];
        bh4 o;
        o[0] = (__bf16)v.x; o[1] = (__bf16)v.y; o[2] = (__bf16)v.z; o[3] = (__bf16)v.w;
        ((bh4*)out)[i] = o;
    }
}

// ---------------- LayerNorm (fp32 in -> bf16 out), one block per row, D=1024 ----------------
__global__ __launch_bounds__(256) void ln_k(const float* __restrict__ x,
                                            const float* __restrict__ g,
                                            const float* __restrict__ bb,
                                            __bf16* __restrict__ out) {
    const int row = blockIdx.x, t = threadIdx.x;
    const float4 v = ((const float4*)(x + (size_t)row * Dz))[t];
    float s = v.x + v.y + v.z + v.w;
    float s2 = v.x * v.x + v.y * v.y + v.z * v.z + v.w * v.w;
#pragma unroll
    for (int off = 32; off > 0; off >>= 1) {
        s += __shfl_down(s, off);
        s2 += __shfl_down(s2, off);
    }
    __shared__ float ps[4], ps2[4];
    if ((t & 63) == 0) { ps[t >> 6] = s; ps2[t >> 6] = s2; }
    __syncthreads();
    float ts = 0.f, ts2 = 0.f;
#pragma unroll
    for (int i = 0; i < 4; i++) { ts += ps[i]; ts2 += ps2[i]; }
    const float mean = ts * (1.f / Dz);
    const float var = ts2 * (1.f / Dz) - mean * mean;
    const float inv = rsqrtf(var + 1e-5f);
    const float4 gv = ((const float4*)g)[t];
    const float4 bv = ((const float4*)bb)[t];
    bh4 o;
    o[0] = (__bf16)((v.x - mean) * inv * gv.x + bv.x);
    o[1] = (__bf16)((v.y - mean) * inv * gv.y + bv.y);
    o[2] = (__bf16)((v.z - mean) * inv * gv.z + bv.z);
    o[3] = (__bf16)((v.w - mean) * inv * gv.w + bv.w);
    *(bh4*)&out[(size_t)row * Dz + t * 4] = o;
}

// ---------------- 128x128-tile bf16 GEMM, C = A[M,K] * W[N,K]^T (+epilogue) ----------------
// EPI 0: outb = bf16(acc + bias)
// EPI 1/2: outf = addf + acc + bias      (fp32 residual write)
// EPI 3: outb = bf16( silu(acc+bias) * up ), up read+written in place allowed
template <int EPI>
__global__ __launch_bounds__(256) void gemm128(
    const __bf16* __restrict__ A, const __bf16* __restrict__ W,
    const float* __restrict__ bias, void* __restrict__ outp,
    const float* __restrict__ addf, const __bf16* __restrict__ upb,
    int M, int N, int K) {
    __shared__ __align__(16) __bf16 lsA[128 * 32];
    __shared__ __align__(16) __bf16 lsB[128 * 32];
    const int t = threadIdx.x;
    const int w = t >> 6, l = t & 63;
    const int brow = blockIdx.y, bcol = blockIdx.x;

    const __bf16* Ag = A + (size_t)(brow * 128 + (t >> 2)) * K + (t & 3) * 8;
    const __bf16* Wg = W + (size_t)(bcol * 128 + (t >> 2)) * K + (t & 3) * 8;
    __bf16* lA0 = lsA + w * 512;  // wave-uniform LDS staging base
    __bf16* lB0 = lsB + w * 512;

    const f4 zf = {0.f, 0.f, 0.f, 0.f};
    f4 acc[4][4];
#pragma unroll
    for (int m = 0; m < 4; m++)
#pragma unroll
        for (int n = 0; n < 4; n++) acc[m][n] = zf;

    const int lo = l & 15, hi = l >> 4;
    const int rowA = (w >> 1) * 64 + lo;
    const int colB = (w & 1) * 64 + lo;
    const int kk = hi * 8;

    for (int k0 = 0; k0 < K; k0 += 32) {
        GLOAD16(Ag + k0, lA0);
        GLOAD16(Ag + (size_t)64 * K + k0, lA0 + 64 * 32);
        GLOAD16(Wg + k0, lB0);
        GLOAD16(Wg + (size_t)64 * K + k0, lB0 + 64 * 32);
        __syncthreads();
        bh8 af[4], bfv[4];
#pragma unroll
        for (int m = 0; m < 4; m++) af[m] = *(const bh8*)&lsA[(rowA + m * 16) * 32 + kk];
#pragma unroll
        for (int n = 0; n < 4; n++) bfv[n] = *(const bh8*)&lsB[(colB + n * 16) * 32 + kk];
#pragma unroll
        for (int m = 0; m < 4; m++)
#pragma unroll
            for (int n = 0; n < 4; n++)
                acc[m][n] = __builtin_amdgcn_mfma_f32_16x16x32_bf16(af[m], bfv[n], acc[m][n], 0, 0, 0);
        __syncthreads();
    }

    const int gr0 = brow * 128 + (w >> 1) * 64;
    const int gc0 = bcol * 128 + (w & 1) * 64;
#pragma unroll
    for (int m = 0; m < 4; m++)
#pragma unroll
        for (int n = 0; n < 4; n++) {
            const int col = gc0 + n * 16 + lo;
            const float bv = bias[col];
#pragma unroll
            for (int j = 0; j < 4; j++) {
                const int row = gr0 + m * 16 + hi * 4 + j;
                const size_t idx = (size_t)row * N + col;
                const float v = acc[m][n][j] + bv;
                if (EPI == 0) {
                    ((__bf16*)outp)[idx] = (__bf16)v;
                } else if (EPI == 1 || EPI == 2) {
                    ((float*)outp)[idx] = addf[idx] + v;
                } else {
                    const float u = (float)upb[idx];
                    const float sv = v / (1.f + __expf(-v));
                    ((__bf16*)outp)[idx] = (__bf16)(sv * u);
                }
            }
        }
}

// ---------------- Flash attention with ALiBi ----------------
// grid (N/64, H, B), 256 threads = 4 waves; wave w owns 16 q-rows.
__global__ __launch_bounds__(256) void attn_k(const __bf16* __restrict__ qkv,
                                              __bf16* __restrict__ out) {
    const int t = threadIdx.x, w = t >> 6, l = t & 63;
    const int qt = blockIdx.x, h = blockIdx.y, b = blockIdx.z;
    const int qbase = qt * 64;
    const int lo = l & 15, hi = l >> 4;
    const float slope = exp2f(-0.5f * (float)(h + 1));

    const size_t base = (size_t)b * Nz * 3072 + h * 64;
    const __bf16* qp = qkv + base;
    const __bf16* kp = qkv + base + 1024;
    const __bf16* vp = qkv + base + 2048;

    __shared__ __align__(16) __bf16 lsK[64 * 72];
    __shared__ __align__(16) __bf16 lsVt[64 * 72];
    __shared__ __align__(16) __bf16 lsP[4 * 16 * 72];

    const int myq = qbase + w * 16 + lo;  // A-fragment q-row for this lane
    const bh8 qf0 = *(const bh8*)(qp + (size_t)myq * 3072 + hi * 8);
    const bh8 qf1 = *(const bh8*)(qp + (size_t)myq * 3072 + 32 + hi * 8);

    const f4 zf = {0.f, 0.f, 0.f, 0.f};
    float m_run[4], l_run[4];
    f4 oacc[4];
#pragma unroll
    for (int jj = 0; jj < 4; jj++) { m_run[jj] = -1e30f; l_run[jj] = 0.f; }
#pragma unroll
    for (int n = 0; n < 4; n++) oacc[n] = zf;

    for (int j0 = 0; j0 < Nz; j0 += 64) {
        __syncthreads();
        {  // stage K tile [64 j][64 d], padded stride 72 — FULL 64 d per row
            const int jr = t >> 2, d0 = (t & 3) * 16;
            const __bf16* krow = kp + (size_t)(j0 + jr) * 3072 + d0;
            *(bh8*)&lsK[jr * 72 + d0] = *(const bh8*)krow;
            *(bh8*)&lsK[jr * 72 + d0 + 8] = *(const bh8*)(krow + 8);
        }
        {  // stage V transposed: lsVt[d][j], padded stride 72
            const int d = t & 63;
            bh8 t0, t1;
#pragma unroll
            for (int jj = 0; jj < 8; jj++) t0[jj] = vp[(size_t)(j0 + w * 16 + jj) * 3072 + d];
#pragma unroll
            for (int jj = 0; jj < 8; jj++) t1[jj] = vp[(size_t)(j0 + w * 16 + 8 + jj) * 3072 + d];
            *(bh8*)&lsVt[d * 72 + w * 16] = t0;
            *(bh8*)&lsVt[d * 72 + w * 16 + 8] = t1;
        }
        __syncthreads();

        // S = Q K^T over 4 column chunks of 16, + scale + alibi
        float vals[4][4];
#pragma unroll
        for (int c = 0; c < 4; c++) {
            const bh8 kf0 = *(const bh8*)&lsK[(c * 16 + lo) * 72 + hi * 8];
            const bh8 kf1 = *(const bh8*)&lsK[(c * 16 + lo) * 72 + 32 + hi * 8];
            f4 s = zf;
            s = __builtin_amdgcn_mfma_f32_16x16x32_bf16(qf0, kf0, s, 0, 0, 0);
            s = __builtin_amdgcn_mfma_f32_16x16x32_bf16(qf1, kf1, s, 0, 0, 0);
            const int gj = j0 + c * 16 + lo;
#pragma unroll
            for (int jj = 0; jj < 4; jj++) {
                const int gq = qbase + w * 16 + hi * 4 + jj;
                vals[c][jj] = s[jj] * 0.125f - slope * fabsf((float)(gq - gj));
            }
        }
        // online softmax (row = hi*4+jj, spread over 16 lanes of lo)
        float mc[4];
#pragma unroll
        for (int jj = 0; jj < 4; jj++)
            mc[jj] = fmaxf(fmaxf(vals[0][jj], vals[1][jj]), fmaxf(vals[2][jj], vals[3][jj]));
#pragma unroll
        for (int off = 8; off > 0; off >>= 1)
#pragma unroll
            for (int jj = 0; jj < 4; jj++) mc[jj] = fmaxf(mc[jj], __shfl_xor(mc[jj], off));
        float corr[4], psum[4];
#pragma unroll
        for (int jj = 0; jj < 4; jj++) {
            const float mn = fmaxf(m_run[jj], mc[jj]);
            corr[jj] = __expf(m_run[jj] - mn);
            m_run[jj] = mn;
            psum[jj] = 0.f;
        }
#pragma unroll
        for (int c = 0; c < 4; c++)
#pragma unroll
            for (int jj = 0; jj < 4; jj++) {
                const float p = __expf(vals[c][jj] - m_run[jj]);
                vals[c][jj] = p;
                psum[jj] += p;
            }
#pragma unroll
        for (int off = 8; off > 0; off >>= 1)
#pragma unroll
            for (int jj = 0; jj < 4; jj++) psum[jj] += __shfl_xor(psum[jj], off);
#pragma unroll
        for (int jj = 0; jj < 4; jj++) l_run[jj] = l_run[jj] * corr[jj] + psum[jj];
#pragma unroll
        for (int n = 0; n < 4; n++)
#pragma unroll
            for (int jj = 0; jj < 4; jj++) oacc[n][jj] *= corr[jj];

        // P -> LDS (wave-private region) to re-fragment for PV
#pragma unroll
        for (int c = 0; c < 4; c++)
#pragma unroll
            for (int jj = 0; jj < 4; jj++)
                lsP[(w * 16 + hi * 4 + jj) * 72 + c * 16 + lo] = (__bf16)vals[c][jj];

        const bh8 pa0 = *(const bh8*)&lsP[(w * 16 + lo) * 72 + hi * 8];
        const bh8 pa1 = *(const bh8*)&lsP[(w * 16 + lo) * 72 + 32 + hi * 8];
#pragma unroll
        for (int n = 0; n < 4; n++) {
            const bh8 vf0 = *(const bh8*)&lsVt[(n * 16 + lo) * 72 + hi * 8];
            const bh8 vf1 = *(const bh8*)&lsVt[(n * 16 + lo) * 72 + 32 + hi * 8];
            oacc[n] = __builtin_amdgcn_mfma_f32_16x16x32_bf16(pa0, vf0, oacc[n], 0, 0, 0);
            oacc[n] = __builtin_amdgcn_mfma_f32_16x16x32_bf16(pa1, vf1, oacc[n], 0, 0, 0);
        }
    }

#pragma unroll
    for (int n = 0; n < 4; n++)
#pragma unroll
        for (int jj = 0; jj < 4; jj++) {
            const int gq = qbase + w * 16 + hi * 4 + jj;
            const int d = n * 16 + lo;
            out[((size_t)b * Nz + gq) * Dz + h * 64 + d] = (__bf16)(oacc[n][jj] / l_run[jj]);
        }
}

extern "C" void kernel_launch(void* const* d_in, const int* in_sizes, int n_in,
                              void* d_out, int out_size, void* d_ws, size_t ws_size,
                              hipStream_t stream) {
    const float* src  = (const float*)d_in[0];
    const float* wqkv = (const float*)d_in[1];
    const float* bqkv = (const float*)d_in[2];
    const float* wo   = (const float*)d_in[3];
    const float* bo   = (const float*)d_in[4];
    const float* g1   = (const float*)d_in[5];
    const float* b1   = (const float*)d_in[6];
    const float* g2   = (const float*)d_in[7];
    const float* b2   = (const float*)d_in[8];
    const float* wg   = (const float*)d_in[9];
    const float* bg   = (const float*)d_in[10];
    const float* wu   = (const float*)d_in[11];
    const float* bu   = (const float*)d_in[12];
    const float* wd   = (const float*)d_in[13];
    const float* bd   = (const float*)d_in[14];
    float* out = (float*)d_out;

    // workspace layout (bf16 elements unless noted)
    __bf16* wqkv_b = (__bf16*)d_ws;                       // 3072*1024
    __bf16* wo_b   = wqkv_b + (size_t)3072 * 1024;        // 1024*1024
    __bf16* wg_b   = wo_b + (size_t)1024 * 1024;          // 4096*1024
    __bf16* wu_b   = wg_b + (size_t)4096 * 1024;          // 4096*1024
    __bf16* wd_b   = wu_b + (size_t)4096 * 1024;          // 1024*4096
    __bf16* lnbuf  = wd_b + (size_t)1024 * 4096;          // 8192*1024 (LN1 then LN2)
    __bf16* qkv    = lnbuf + (size_t)8192 * 1024;         // 8192*3072
    __bf16* attno  = qkv + (size_t)8192 * 3072;           // 8192*1024
    float*  x1     = (float*)(attno + (size_t)8192 * 1024);  // 8192*1024 fp32
    __bf16* hb     = qkv;  // reuse dead qkv+attno region: 8192*4096 bf16 (exact fit)

    // weight conversion
    cvt_k<<<3072, 256, 0, stream>>>(wqkv, wqkv_b, 3072 * 1024 / 4);
    cvt_k<<<1024, 256, 0, stream>>>(wo, wo_b, 1024 * 1024 / 4);
    cvt_k<<<4096, 256, 0, stream>>>(wg, wg_b, 4096 * 1024 / 4);
    cvt_k<<<4096, 256, 0, stream>>>(wu, wu_b, 4096 * 1024 / 4);
    cvt_k<<<4096, 256, 0, stream>>>(wd, wd_b, 1024 * 4096 / 4);

    // x = src + attn(LN1(src))
    ln_k<<<8192, 256, 0, stream>>>(src, g1, b1, lnbuf);
    gemm128<0><<<dim3(3072 / 128, 8192 / 128), 256, 0, stream>>>(
        lnbuf, wqkv_b, bqkv, qkv, nullptr, nullptr, 8192, 3072, 1024);
    attn_k<<<dim3(16, 16, 8), 256, 0, stream>>>(qkv, attno);
    gemm128<1><<<dim3(1024 / 128, 8192 / 128), 256, 0, stream>>>(
        attno, wo_b, bo, x1, src, nullptr, 8192, 1024, 1024);

    // x = x + swiglu(LN2(x))
    ln_k<<<8192, 256, 0, stream>>>(x1, g2, b2, lnbuf);
    gemm128<0><<<dim3(4096 / 128, 8192 / 128), 256, 0, stream>>>(
        lnbuf, wu_b, bu, hb, nullptr, nullptr, 8192, 4096, 1024);
    gemm128<3><<<dim3(4096 / 128, 8192 / 128), 256, 0, stream>>>(
        lnbuf, wg_b, bg, hb, nullptr, hb, 8192, 4096, 1024);
    gemm128<2><<<dim3(1024 / 128, 8192 / 128), 256, 0, stream>>>(
        hb, wd_b, bd, out, x1, nullptr, 8192, 1024, 4096);
}

// Round 4
// 726.743 us; speedup vs baseline: 1.0400x; 1.0400x over previous
//
#include <hip/hip_runtime.h>

#define Bz 8
#define Nz 1024
#define Dz 1024
#define Hz 16
#define HDz 64
#define DFFz 4096

typedef __attribute__((ext_vector_type(8))) __bf16 bh8;
typedef __attribute__((ext_vector_type(4))) __bf16 bh4;
typedef __attribute__((ext_vector_type(4))) float f4;

#define GLOAD16(gp, lp) __builtin_amdgcn_global_load_lds( \
    (__attribute__((address_space(1))) void*)(gp), \
    (__attribute__((address_space(3))) void*)(lp), 16, 0, 0)

// ---------------- fp32 -> bf16 convert ----------------
__global__ __launch_bounds__(256) void cvt_k(const float* __restrict__ in,
                                             __bf16* __restrict__ out, int n4) {
    int i = blockIdx.x * 256 + threadIdx.x;
    if (i < n4) {
        float4 v = ((const float4*)in)[i];
        bh4 o;
        o[0] = (__bf16)v.x; o[1] = (__bf16)v.y; o[2] = (__bf16)v.z; o[3] = (__bf16)v.w;
        ((bh4*)out)[i] = o;
    }
}

// ---------------- LayerNorm (fp32 in -> bf16 out), one block per row, D=1024 ----------------
__global__ __launch_bounds__(256) void ln_k(const float* __restrict__ x,
                                            const float* __restrict__ g,
                                            const float* __restrict__ bb,
                                            __bf16* __restrict__ out) {
    const int row = blockIdx.x, t = threadIdx.x;
    const float4 v = ((const float4*)(x + (size_t)row * Dz))[t];
    float s = v.x + v.y + v.z + v.w;
    float s2 = v.x * v.x + v.y * v.y + v.z * v.z + v.w * v.w;
#pragma unroll
    for (int off = 32; off > 0; off >>= 1) {
        s += __shfl_down(s, off);
        s2 += __shfl_down(s2, off);
    }
    __shared__ float ps[4], ps2[4];
    if ((t & 63) == 0) { ps[t >> 6] = s; ps2[t >> 6] = s2; }
    __syncthreads();
    float ts = 0.f, ts2 = 0.f;
#pragma unroll
    for (int i = 0; i < 4; i++) { ts += ps[i]; ts2 += ps2[i]; }
    const float mean = ts * (1.f / Dz);
    const float var = ts2 * (1.f / Dz) - mean * mean;
    const float inv = rsqrtf(var + 1e-5f);
    const float4 gv = ((const float4*)g)[t];
    const float4 bv = ((const float4*)bb)[t];
    bh4 o;
    o[0] = (__bf16)((v.x - mean) * inv * gv.x + bv.x);
    o[1] = (__bf16)((v.y - mean) * inv * gv.y + bv.y);
    o[2] = (__bf16)((v.z - mean) * inv * gv.z + bv.z);
    o[3] = (__bf16)((v.w - mean) * inv * gv.w + bv.w);
    *(bh4*)&out[(size_t)row * Dz + t * 4] = o;
}

// ---------------- 128x128-tile bf16 GEMM, 2-phase double-buffered (T3-min) ----------------
// C = A[M,K] * W[N,K]^T (+epilogue)
template <int EPI>
__global__ __launch_bounds__(256) void gemm128(
    const __bf16* __restrict__ A, const __bf16* __restrict__ W,
    const float* __restrict__ bias, void* __restrict__ outp,
    const float* __restrict__ addf, const __bf16* __restrict__ upb,
    int M, int N, int K) {
    __shared__ __align__(16) __bf16 lsA[2 * 128 * 32];
    __shared__ __align__(16) __bf16 lsB[2 * 128 * 32];
    const int t = threadIdx.x;
    const int w = t >> 6, l = t & 63;
    const int brow = blockIdx.y, bcol = blockIdx.x;

    const __bf16* Ag = A + (size_t)(brow * 128 + (t >> 2)) * K + (t & 3) * 8;
    const __bf16* Wg = W + (size_t)(bcol * 128 + (t >> 2)) * K + (t & 3) * 8;

    const f4 zf = {0.f, 0.f, 0.f, 0.f};
    f4 acc[4][4];
#pragma unroll
    for (int m = 0; m < 4; m++)
#pragma unroll
        for (int n = 0; n < 4; n++) acc[m][n] = zf;

    const int lo = l & 15, hi = l >> 4;
    const int rowA = (w >> 1) * 64 + lo;
    const int colB = (w & 1) * 64 + lo;
    const int kk = hi * 8;

#define STAGE(P, KOFF) do { \
        GLOAD16(Ag + (KOFF), lsA + (P) * 4096 + w * 512); \
        GLOAD16(Ag + (size_t)64 * K + (KOFF), lsA + (P) * 4096 + w * 512 + 64 * 32); \
        GLOAD16(Wg + (KOFF), lsB + (P) * 4096 + w * 512); \
        GLOAD16(Wg + (size_t)64 * K + (KOFF), lsB + (P) * 4096 + w * 512 + 64 * 32); \
    } while (0)

#define COMPUTE(P) do { \
        const __bf16* la = lsA + (P) * 4096; \
        const __bf16* lb = lsB + (P) * 4096; \
        bh8 af[4], bfv[4]; \
        _Pragma("unroll") \
        for (int m = 0; m < 4; m++) af[m] = *(const bh8*)&la[(rowA + m * 16) * 32 + kk]; \
        _Pragma("unroll") \
        for (int n = 0; n < 4; n++) bfv[n] = *(const bh8*)&lb[(colB + n * 16) * 32 + kk]; \
        _Pragma("unroll") \
        for (int m = 0; m < 4; m++) \
            _Pragma("unroll") \
            for (int n = 0; n < 4; n++) \
                acc[m][n] = __builtin_amdgcn_mfma_f32_16x16x32_bf16(af[m], bfv[n], acc[m][n], 0, 0, 0); \
    } while (0)

    const int nt = K >> 5;
    int cur = 0;
    STAGE(0, 0);
    __syncthreads();  // compiler drains vmcnt before s_barrier
    for (int kt = 0; kt < nt - 1; ++kt) {
        STAGE(cur ^ 1, (kt + 1) * 32);  // issue next-tile loads, fly during MFMA
        COMPUTE(cur);
        __syncthreads();  // drains this wave's vmcnt (next tile landed) + orders buffers
        cur ^= 1;
    }
    COMPUTE(cur);
#undef STAGE
#undef COMPUTE

    const int gr0 = brow * 128 + (w >> 1) * 64;
    const int gc0 = bcol * 128 + (w & 1) * 64;
#pragma unroll
    for (int m = 0; m < 4; m++)
#pragma unroll
        for (int n = 0; n < 4; n++) {
            const int col = gc0 + n * 16 + lo;
            const float bv = bias[col];
#pragma unroll
            for (int j = 0; j < 4; j++) {
                const int row = gr0 + m * 16 + hi * 4 + j;
                const size_t idx = (size_t)row * N + col;
                const float v = acc[m][n][j] + bv;
                if (EPI == 0) {
                    ((__bf16*)outp)[idx] = (__bf16)v;
                } else if (EPI == 1 || EPI == 2) {
                    ((float*)outp)[idx] = addf[idx] + v;
                } else {
                    const float u = (float)upb[idx];
                    const float sv = v / (1.f + __expf(-v));
                    ((__bf16*)outp)[idx] = (__bf16)(sv * u);
                }
            }
        }
}

// ---------------- Flash attention with ALiBi ----------------
// grid (N/64, H, B), 256 threads = 4 waves; wave w owns 16 q-rows.
// lsK: [64 j][64 d], chunk-XOR swizzled: chunk c8 of row j stored at c8^(j&7)
// lsVt: [64 d][64+8 j] transposed, padded stride 72 (round-2 known-good)
// lsP: per-wave [16 q][64 j], elem = w*1024 + q*64 + (j ^ ((q&7)*8))
__global__ __launch_bounds__(256) void attn_k(const __bf16* __restrict__ qkv,
                                              __bf16* __restrict__ out) {
    const int t = threadIdx.x, w = t >> 6, l = t & 63;
    const int qt = blockIdx.x, h = blockIdx.y, b = blockIdx.z;
    const int qbase = qt * 64;
    const int lo = l & 15, hi = l >> 4;
    const float slope = exp2f(-0.5f * (float)(h + 1));

    const size_t base = (size_t)b * Nz * 3072 + h * 64;
    const __bf16* qp = qkv + base;
    const __bf16* kp = qkv + base + 1024;
    const __bf16* vp = qkv + base + 2048;

    __shared__ __align__(16) __bf16 lsK[64 * 64];
    __shared__ __align__(16) __bf16 lsVt[64 * 72];
    __shared__ __align__(16) __bf16 lsP[4 * 16 * 64];

    const int myq = qbase + w * 16 + lo;
    const bh8 qf0 = *(const bh8*)(qp + (size_t)myq * 3072 + hi * 8);
    const bh8 qf1 = *(const bh8*)(qp + (size_t)myq * 3072 + 32 + hi * 8);

    const f4 zf = {0.f, 0.f, 0.f, 0.f};
    float m_run[4], l_run[4];
    f4 oacc[4];
#pragma unroll
    for (int jj = 0; jj < 4; jj++) { m_run[jj] = -1e30f; l_run[jj] = 0.f; }
#pragma unroll
    for (int n = 0; n < 4; n++) oacc[n] = zf;

    const int jr = t >> 2, d0 = (t & 3) * 16;

    for (int j0 = 0; j0 < Nz; j0 += 64) {
        __syncthreads();
        {  // stage K tile, XOR-swizzled rows (audited)
            const __bf16* krow = kp + (size_t)(j0 + jr) * 3072 + d0;
            const int sw = (jr & 7) * 8;
            *(bh8*)&lsK[jr * 64 + (d0 ^ sw)] = *(const bh8*)krow;
            *(bh8*)&lsK[jr * 64 + ((d0 + 8) ^ sw)] = *(const bh8*)(krow + 8);
        }
        {  // stage V transposed: lsVt[d][j], padded stride 72 (round-2 known-good)
            const int d = t & 63;
            bh8 t0, t1;
#pragma unroll
            for (int jj = 0; jj < 8; jj++) t0[jj] = vp[(size_t)(j0 + w * 16 + jj) * 3072 + d];
#pragma unroll
            for (int jj = 0; jj < 8; jj++) t1[jj] = vp[(size_t)(j0 + w * 16 + 8 + jj) * 3072 + d];
            *(bh8*)&lsVt[d * 72 + w * 16] = t0;
            *(bh8*)&lsVt[d * 72 + w * 16 + 8] = t1;
        }
        __syncthreads();

        // S = Q K^T over 4 column chunks of 16, + scale + alibi
        float vals[4][4];
#pragma unroll
        for (int c = 0; c < 4; c++) {
            const int krw = c * 16 + lo;
            const int swr = (krw & 7);
            const bh8 kf0 = *(const bh8*)&lsK[krw * 64 + 8 * (hi ^ swr)];
            const bh8 kf1 = *(const bh8*)&lsK[krw * 64 + 8 * ((4 + hi) ^ swr)];
            f4 s = zf;
            s = __builtin_amdgcn_mfma_f32_16x16x32_bf16(qf0, kf0, s, 0, 0, 0);
            s = __builtin_amdgcn_mfma_f32_16x16x32_bf16(qf1, kf1, s, 0, 0, 0);
            const int gj = j0 + c * 16 + lo;
#pragma unroll
            for (int jj = 0; jj < 4; jj++) {
                const int gq = qbase + w * 16 + hi * 4 + jj;
                vals[c][jj] = s[jj] * 0.125f - slope * fabsf((float)(gq - gj));
            }
        }
        // online softmax (row = hi*4+jj, spread over 16 lanes of lo)
        float mc[4];
#pragma unroll
        for (int jj = 0; jj < 4; jj++)
            mc[jj] = fmaxf(fmaxf(vals[0][jj], vals[1][jj]), fmaxf(vals[2][jj], vals[3][jj]));
#pragma unroll
        for (int off = 8; off > 0; off >>= 1)
#pragma unroll
            for (int jj = 0; jj < 4; jj++) mc[jj] = fmaxf(mc[jj], __shfl_xor(mc[jj], off));
        float corr[4], psum[4];
#pragma unroll
        for (int jj = 0; jj < 4; jj++) {
            const float mn = fmaxf(m_run[jj], mc[jj]);
            corr[jj] = __expf(m_run[jj] - mn);
            m_run[jj] = mn;
            psum[jj] = 0.f;
        }
#pragma unroll
        for (int c = 0; c < 4; c++)
#pragma unroll
            for (int jj = 0; jj < 4; jj++) {
                const float p = __expf(vals[c][jj] - m_run[jj]);
                vals[c][jj] = p;
                psum[jj] += p;
            }
#pragma unroll
        for (int off = 8; off > 0; off >>= 1)
#pragma unroll
            for (int jj = 0; jj < 4; jj++) psum[jj] += __shfl_xor(psum[jj], off);
#pragma unroll
        for (int jj = 0; jj < 4; jj++) l_run[jj] = l_run[jj] * corr[jj] + psum[jj];
#pragma unroll
        for (int n = 0; n < 4; n++)
#pragma unroll
            for (int jj = 0; jj < 4; jj++) oacc[n][jj] *= corr[jj];

        // P -> LDS (wave-private, XOR-swizzled, audited)
#pragma unroll
        for (int c = 0; c < 4; c++)
#pragma unroll
            for (int jj = 0; jj < 4; jj++) {
                const int q = hi * 4 + jj;
                lsP[w * 1024 + q * 64 + ((c * 16 + lo) ^ ((q & 7) * 8))] = (__bf16)vals[c][jj];
            }

        const int psw = (lo & 7);
        const bh8 pa0 = *(const bh8*)&lsP[w * 1024 + lo * 64 + 8 * (hi ^ psw)];
        const bh8 pa1 = *(const bh8*)&lsP[w * 1024 + lo * 64 + 8 * ((4 + hi) ^ psw)];

#pragma unroll
        for (int n = 0; n < 4; n++) {
            const bh8 vf0 = *(const bh8*)&lsVt[(n * 16 + lo) * 72 + hi * 8];
            const bh8 vf1 = *(const bh8*)&lsVt[(n * 16 + lo) * 72 + 32 + hi * 8];
            oacc[n] = __builtin_amdgcn_mfma_f32_16x16x32_bf16(pa0, vf0, oacc[n], 0, 0, 0);
            oacc[n] = __builtin_amdgcn_mfma_f32_16x16x32_bf16(pa1, vf1, oacc[n], 0, 0, 0);
        }
    }

#pragma unroll
    for (int n = 0; n < 4; n++)
#pragma unroll
        for (int jj = 0; jj < 4; jj++) {
            const int gq = qbase + w * 16 + hi * 4 + jj;
            const int d = n * 16 + lo;
            out[((size_t)b * Nz + gq) * Dz + h * 64 + d] = (__bf16)(oacc[n][jj] / l_run[jj]);
        }
}

extern "C" void kernel_launch(void* const* d_in, const int* in_sizes, int n_in,
                              void* d_out, int out_size, void* d_ws, size_t ws_size,
                              hipStream_t stream) {
    const float* src  = (const float*)d_in[0];
    const float* wqkv = (const float*)d_in[1];
    const float* bqkv = (const float*)d_in[2];
    const float* wo   = (const float*)d_in[3];
    const float* bo   = (const float*)d_in[4];
    const float* g1   = (const float*)d_in[5];
    const float* b1   = (const float*)d_in[6];
    const float* g2   = (const float*)d_in[7];
    const float* b2   = (const float*)d_in[8];
    const float* wg   = (const float*)d_in[9];
    const float* bg   = (const float*)d_in[10];
    const float* wu   = (const float*)d_in[11];
    const float* bu   = (const float*)d_in[12];
    const float* wd   = (const float*)d_in[13];
    const float* bd   = (const float*)d_in[14];
    float* out = (float*)d_out;

    __bf16* wqkv_b = (__bf16*)d_ws;                       // 3072*1024
    __bf16* wo_b   = wqkv_b + (size_t)3072 * 1024;        // 1024*1024
    __bf16* wg_b   = wo_b + (size_t)1024 * 1024;          // 4096*1024
    __bf16* wu_b   = wg_b + (size_t)4096 * 1024;          // 4096*1024
    __bf16* wd_b   = wu_b + (size_t)4096 * 1024;          // 1024*4096
    __bf16* lnbuf  = wd_b + (size_t)1024 * 4096;          // 8192*1024
    __bf16* qkv    = lnbuf + (size_t)8192 * 1024;         // 8192*3072
    __bf16* attno  = qkv + (size_t)8192 * 3072;           // 8192*1024
    float*  x1     = (float*)(attno + (size_t)8192 * 1024);  // 8192*1024 fp32
    __bf16* hb     = qkv;  // reuse dead qkv+attno region: 8192*4096 bf16

    cvt_k<<<3072, 256, 0, stream>>>(wqkv, wqkv_b, 3072 * 1024 / 4);
    cvt_k<<<1024, 256, 0, stream>>>(wo, wo_b, 1024 * 1024 / 4);
    cvt_k<<<4096, 256, 0, stream>>>(wg, wg_b, 4096 * 1024 / 4);
    cvt_k<<<4096, 256, 0, stream>>>(wu, wu_b, 4096 * 1024 / 4);
    cvt_k<<<4096, 256, 0, stream>>>(wd, wd_b, 1024 * 4096 / 4);

    ln_k<<<8192, 256, 0, stream>>>(src, g1, b1, lnbuf);
    gemm128<0><<<dim3(3072 / 128, 8192 / 128), 256, 0, stream>>>(
        lnbuf, wqkv_b, bqkv, qkv, nullptr, nullptr, 8192, 3072, 1024);
    attn_k<<<dim3(16, 16, 8), 256, 0, stream>>>(qkv, attno);
    gemm128<1><<<dim3(1024 / 128, 8192 / 128), 256, 0, stream>>>(
        attno, wo_b, bo, x1, src, nullptr, 8192, 1024, 1024);

    ln_k<<<8192, 256, 0, stream>>>(x1, g2, b2, lnbuf);
    gemm128<0><<<dim3(4096 / 128, 8192 / 128), 256, 0, stream>>>(
        lnbuf, wu_b, bu, hb, nullptr, nullptr, 8192, 4096, 1024);
    gemm128<3><<<dim3(4096 / 128, 8192 / 128), 256, 0, stream>>>(
        lnbuf, wg_b, bg, hb, nullptr, hb, 8192, 4096, 1024);
    gemm128<2><<<dim3(1024 / 128, 8192 / 128), 256, 0, stream>>>(
        hb, wd_b, bd, out, x1, nullptr, 8192, 1024, 4096);
}